// Round 2
// baseline (833.846 us; speedup 1.0000x reference)
//
#include <hip/hip_runtime.h>
#include <math.h>

static inline int cdiv(long long a, int b){ return (int)((a + b - 1) / b); }

// ---------- gather table build: g[i*27+k] = input idx j, or -1 ----------
__global__ void k_ginit(int* __restrict__ g, int n){
  int idx = blockIdx.x*blockDim.x + threadIdx.x;
  if (idx < n) g[idx] = -1;
}

__global__ void k_gbuild(const int* __restrict__ nin, const int* __restrict__ nout,
                         int* __restrict__ g, int P, int n_out){
  int p = blockIdx.x*blockDim.x + threadIdx.x;
  if (p >= 27*P) return;
  int oi = nout[p];
  if (oi >= n_out) return;       // padded slot
  int k = p / P;
  g[oi*27 + k] = nin[p];         // each (oi,k) occurs at most once -> no atomics
}

// ---------- up-projection: f[n*8+k][d] = relu(x[n]·W_up[k][:,d] + b_up[d]) ----------
__global__ void k_up(const float* __restrict__ x, const float* __restrict__ Wup,
                     const float* __restrict__ bup, float* __restrict__ outr, int n_out){
  int idx = blockIdx.x*blockDim.x + threadIdx.x;
  if (idx >= n_out*32) return;
  int row = idx >> 5, d = idx & 31;
  int n = row >> 3, k = row & 7;
  const float* xr = x + n*64;
  const float* w  = Wup + k*(64*32) + d;
  float s = bup[d];
#pragma unroll
  for (int c = 0; c < 64; ++c) s = fmaf(xr[c], w[c*32], s);
  outr[idx] = fmaxf(s, 0.f);
}

// ---------- gather-based sparse conv, fused bias(+relu)(+residual-add) ----------
// out[i*OSTRIDE + OFFS + c] (=|+=) relu?( b[c] + sum_k sum_cin fin[g[i][k]][cin]*W[k][cin][c] )
template<int CIN, int COUT, bool RELU, bool ADD, int OFFS, int OSTRIDE>
__global__ void k_gconv(const float* __restrict__ fin, const float* __restrict__ W,
                        const float* __restrict__ b, const int* __restrict__ g,
                        float* __restrict__ fout, int n_out){
  int idx = blockIdx.x*blockDim.x + threadIdx.x;
  if (idx >= n_out*COUT) return;
  int i = idx / COUT, c = idx - (idx / COUT)*COUT;
  const int* gi = g + i*27;
  float s = b[c];
  for (int k = 0; k < 27; ++k){
    int j = gi[k];
    if (j < 0) continue;
    const float* fr = fin + (size_t)j*CIN;
    const float* w  = W + (size_t)k*CIN*COUT + c;
#pragma unroll
    for (int cc = 0; cc < CIN; ++cc) s = fmaf(fr[cc], w[cc*COUT], s);
  }
  if (RELU) s = fmaxf(s, 0.f);
  float* o = fout + (size_t)i*OSTRIDE + OFFS + c;
  if (ADD) *o += s; else *o = s;
}

// ---------- dense per-row GEMV, fused bias(+relu)(+residual-add) ----------
template<int CIN, int COUT, bool RELU, bool ADD, int OFFS, int OSTRIDE>
__global__ void k_dense(const float* __restrict__ fin, const float* __restrict__ W,
                        const float* __restrict__ b, float* __restrict__ fout, int n_out){
  int idx = blockIdx.x*blockDim.x + threadIdx.x;
  if (idx >= n_out*COUT) return;
  int i = idx / COUT, c = idx - (idx / COUT)*COUT;
  const float* fr = fin + (size_t)i*CIN;
  float s = b[c];
#pragma unroll
  for (int cc = 0; cc < CIN; ++cc) s = fmaf(fr[cc], W[cc*COUT + c], s);
  if (RELU) s = fmaxf(s, 0.f);
  float* o = fout + (size_t)i*OSTRIDE + OFFS + c;
  if (ADD) *o += s; else *o = s;
}

// ---------- max/argmax reduction (first-index tie-break, matches jnp.argmax) ----------
__global__ void k_reduce1(const float* __restrict__ s, float* __restrict__ pmax,
                          int* __restrict__ pidx, int n){
  __shared__ float sm[256]; __shared__ int si[256];
  int t = threadIdx.x;
  float v = -INFINITY; int vi = 0x7fffffff;
  for (int j = blockIdx.x*256 + t; j < n; j += gridDim.x*256){
    float w = s[j];
    if (w > v){ v = w; vi = j; }
  }
  sm[t] = v; si[t] = vi; __syncthreads();
  for (int o = 128; o > 0; o >>= 1){
    if (t < o){
      if (sm[t+o] > sm[t] || (sm[t+o] == sm[t] && si[t+o] < si[t])){ sm[t]=sm[t+o]; si[t]=si[t+o]; }
    }
    __syncthreads();
  }
  if (t == 0){ pmax[blockIdx.x] = sm[0]; pidx[blockIdx.x] = si[0]; }
}

__global__ void k_reduce2(const float* __restrict__ pmax, const int* __restrict__ pidx,
                          float* __restrict__ g, int nb){
  __shared__ float sm[256]; __shared__ int si[256];
  int t = threadIdx.x;
  sm[t] = (t < nb) ? pmax[t] : -INFINITY;
  si[t] = (t < nb) ? pidx[t] : 0x7fffffff;
  __syncthreads();
  for (int o = 128; o > 0; o >>= 1){
    if (t < o){
      if (sm[t+o] > sm[t] || (sm[t+o] == sm[t] && si[t+o] < si[t])){ sm[t]=sm[t+o]; si[t]=si[t+o]; }
    }
    __syncthreads();
  }
  if (t == 0){ g[0] = sm[0]; ((int*)g)[1] = si[0]; }
}

// ---------- finalize: keep mask, pruned out, flat output assembly ----------
__global__ void k_final(const float* __restrict__ out, const float* __restrict__ cls,
                        const int* __restrict__ target, const float* __restrict__ g,
                        float* __restrict__ dout, int n_out){
  int idx = blockIdx.x*blockDim.x + threadIdx.x;
  if (idx >= n_out*32) return;
  int row = idx >> 5, c = idx & 31;
  float s = cls[row];
  bool keep = s > 0.f;
  if (g[0] < 0.f) keep = keep || (row == ((const int*)g)[1]);
  float km = keep ? 1.f : 0.f;
  dout[idx] = out[idx] * km;
  if (c == 0){
    dout[(size_t)n_out*32 + row] = s;
    dout[(size_t)n_out*33 + row] = (target[row] != 0) ? 1.f : 0.f;
    dout[(size_t)n_out*34 + row] = km;
  }
}

extern "C" void kernel_launch(void* const* d_in, const int* in_sizes, int n_in,
                              void* d_out, int out_size, void* d_ws, size_t ws_size,
                              hipStream_t stream){
  const float* x      = (const float*)d_in[0];
  const float* W_up   = (const float*)d_in[1];
  const float* b_up   = (const float*)d_in[2];
  const float* W_conv = (const float*)d_in[3];
  const float* b_conv = (const float*)d_in[4];
  const float* Wb00   = (const float*)d_in[5];
  const float* bb00   = (const float*)d_in[6];
  const float* Wb01   = (const float*)d_in[7];
  const float* bb01   = (const float*)d_in[8];
  const float* Wb10   = (const float*)d_in[9];
  const float* bb10   = (const float*)d_in[10];
  const float* Wb11   = (const float*)d_in[11];
  const float* bb11   = (const float*)d_in[12];
  const float* Wb12   = (const float*)d_in[13];
  const float* bb12   = (const float*)d_in[14];
  const float* W_cls  = (const float*)d_in[15];
  const float* b_cls  = (const float*)d_in[16];
  const int*   nbr_in = (const int*)d_in[17];
  const int*   nbr_out= (const int*)d_in[18];
  const int*   target = (const int*)d_in[19];

  const int n_out = in_sizes[19];
  const int P     = in_sizes[17] / 27;
  const int pairsT = 27 * P;

  // workspace layout
  int*   g     = (int*)d_ws;                          // N*27 ints
  float* ws    = (float*)d_ws + (size_t)n_out*27;
  float* f_out = ws;                                  // N*32
  float* f_tmp = ws + (size_t)n_out*32;               // N*32
  float* a8    = ws + (size_t)n_out*64;               // N*8
  float* b8    = ws + (size_t)n_out*72;               // N*8
  float* cls   = ws + (size_t)n_out*80;               // N
  float* pmax  = ws + (size_t)n_out*81;               // 256
  int*   pidx  = (int*)(ws + (size_t)n_out*81 + 256); // 256
  float* gm    = ws + (size_t)n_out*81 + 512;         // [max, argmax]

  const int B = 256;

  // build gather table
  k_ginit<<<cdiv((long long)n_out*27,B),B,0,stream>>>(g, n_out*27);
  k_gbuild<<<cdiv((long long)pairsT,B),B,0,stream>>>(nbr_in, nbr_out, g, P, n_out);

  // f_tmp = relu(up)
  k_up<<<cdiv((long long)n_out*32,B),B,0,stream>>>(x, W_up, b_up, f_tmp, n_out);

  // out = relu(sconv(f_tmp, W_conv, b_conv))
  k_gconv<32,32,true,false,0,32><<<cdiv((long long)n_out*32,B),B,0,stream>>>(f_tmp, W_conv, b_conv, g, f_out, n_out);

  for (int l = 0; l < 3; ++l){
    // a8 = relu(sconv(out, Wb00))
    k_gconv<32,8,true,false,0,8><<<cdiv((long long)n_out*8,B),B,0,stream>>>(f_out, Wb00 + (size_t)l*27*32*8, bb00 + l*8, g, a8, n_out);
    // b8 = relu(out @ Wb10 + b)   (must read f_out BEFORE residual add)
    k_dense<32,8,true,false,0,8><<<cdiv((long long)n_out*8,B),B,0,stream>>>(f_out, Wb10 + (size_t)l*32*8, bb10 + l*8, b8, n_out);
    // out[:, 0:16] += sconv(a8, Wb01) + b
    k_gconv<8,16,false,true,0,32><<<cdiv((long long)n_out*16,B),B,0,stream>>>(a8, Wb01 + (size_t)l*27*8*16, bb01 + l*16, g, f_out, n_out);
    // a8 = relu(sconv(b8, Wb11))
    k_gconv<8,8,true,false,0,8><<<cdiv((long long)n_out*8,B),B,0,stream>>>(b8, Wb11 + (size_t)l*27*8*8, bb11 + l*8, g, a8, n_out);
    // out[:, 16:32] += a8 @ Wb12 + b
    k_dense<8,16,false,true,16,32><<<cdiv((long long)n_out*16,B),B,0,stream>>>(a8, Wb12 + (size_t)l*8*16, bb12 + l*16, f_out, n_out);
  }

  // classifier conv 32->1
  k_gconv<32,1,false,false,0,1><<<cdiv((long long)n_out,B),B,0,stream>>>(f_out, W_cls, b_cls, g, cls, n_out);

  // max/argmax of score
  k_reduce1<<<256,256,0,stream>>>(cls, pmax, pidx, n_out);
  k_reduce2<<<1,256,0,stream>>>(pmax, pidx, gm, 256);

  // assemble outputs
  k_final<<<cdiv((long long)n_out*32,B),B,0,stream>>>(f_out, cls, target, gm, (float*)d_out, n_out);
}

// Round 3
// 341.941 us; speedup vs baseline: 2.4386x; 2.4386x over previous
//
#include <hip/hip_runtime.h>
#include <math.h>

static inline int cdiv(long long a, int b){ return (int)((a + b - 1) / b); }

#define DEVINL __device__ __forceinline__

// ---- load CIN floats of row j into registers (clamped; zeroed if j<0) ----
template<int CIN>
DEVINL void loadrow(float* fv, const float* __restrict__ fin, int j){
  int jj = j < 0 ? 0 : j;
  const float4* p = (const float4*)(fin + (size_t)jj*CIN);
#pragma unroll
  for (int q = 0; q < CIN/4; ++q){
    float4 v = p[q];
    fv[4*q+0]=v.x; fv[4*q+1]=v.y; fv[4*q+2]=v.z; fv[4*q+3]=v.w;
  }
  if (j < 0){
#pragma unroll
    for (int q = 0; q < CIN; ++q) fv[q] = 0.f;
  }
}

// ---- acc[COUT] += fv[CIN] @ Ws[CIN][COUT]  (Ws in LDS, broadcast reads) ----
template<int CIN, int COUT>
DEVINL void fma_block(float* acc, const float* fv, const float* Ws){
#pragma unroll
  for (int cc = 0; cc < CIN; ++cc){
    float f = fv[cc];
    if constexpr ((COUT & 3) == 0){
#pragma unroll
      for (int c4 = 0; c4 < COUT/4; ++c4){
        float4 w = *(const float4*)(Ws + cc*COUT + c4*4);
        acc[c4*4+0] = fmaf(f, w.x, acc[c4*4+0]);
        acc[c4*4+1] = fmaf(f, w.y, acc[c4*4+1]);
        acc[c4*4+2] = fmaf(f, w.z, acc[c4*4+2]);
        acc[c4*4+3] = fmaf(f, w.w, acc[c4*4+3]);
      }
    } else {
#pragma unroll
      for (int c = 0; c < COUT; ++c)
        acc[c] = fmaf(f, Ws[cc*COUT + c], acc[c]);
    }
  }
}

// ---- 27-offset gather conv for one output row, k-loop rolled, fv double-buffered ----
template<int CIN, int COUT>
DEVINL void gconv27(float* acc, const float* __restrict__ fin, const float* Ws,
                    const int* __restrict__ gk, int i, int N){
  float fva[CIN], fvb[CIN];
  loadrow<CIN>(fva, fin, gk[i]);
#pragma unroll 1
  for (int kk = 0; kk + 2 <= 27; kk += 2){
    loadrow<CIN>(fvb, fin, gk[(size_t)(kk+1)*N + i]);
    fma_block<CIN,COUT>(acc, fva, Ws + kk*CIN*COUT);
    int jn = (kk+2 < 27) ? gk[(size_t)(kk+2)*N + i] : -1;
    loadrow<CIN>(fva, fin, jn);
    fma_block<CIN,COUT>(acc, fvb, Ws + (kk+1)*CIN*COUT);
  }
  fma_block<CIN,COUT>(acc, fva, Ws + 26*CIN*COUT);
}

DEVINL void stage_f(float* Ws, const float* __restrict__ Wg, int nf){
  for (int t = threadIdx.x*4; t < nf; t += 256*4)
    *(float4*)&Ws[t] = *(const float4*)&Wg[t];
}

DEVINL float4 relu4(float a, float b, float c, float d){
  return make_float4(fmaxf(a,0.f), fmaxf(b,0.f), fmaxf(c,0.f), fmaxf(d,0.f));
}

// ---------- gather table build (k-major): g[k*N+i] = input idx j, or -1 ----------
__global__ void k_ginit(int* __restrict__ g, int n4){
  int idx = blockIdx.x*blockDim.x + threadIdx.x;
  if (idx < n4){ int4 m = make_int4(-1,-1,-1,-1); ((int4*)g)[idx] = m; }
}

__global__ void k_gbuild(const int* __restrict__ nin, const int* __restrict__ nout,
                         int* __restrict__ g, int P, int n_out){
  int p = blockIdx.x*blockDim.x + threadIdx.x;
  if (p >= 27*P) return;
  int oi = nout[p];
  if (oi >= n_out) return;
  int k = p / P;
  g[(size_t)k*n_out + oi] = nin[p];
}

// ---------- up-projection: f[(n*8+kk)*32+c] = relu(x[n]·W_up[kk][:,c] + b_up[c]) ----------
__global__ __launch_bounds__(256) void k_up(const float* __restrict__ x,
    const float* __restrict__ Wup, const float* __restrict__ bup,
    float* __restrict__ f, int Nn){
  __shared__ float Ws[64*32];
  const int kk = blockIdx.y;
  stage_f(Ws, Wup + (size_t)kk*64*32, 64*32);
  __syncthreads();
  int n = blockIdx.x*blockDim.x + threadIdx.x;
  float xr[64]; loadrow<64>(xr, x, n);
  float acc[32];
#pragma unroll
  for (int c = 0; c < 32; ++c) acc[c] = bup[c];
  fma_block<64,32>(acc, xr, Ws);
  float4* o = (float4*)(f + ((size_t)n*8 + kk)*32);
#pragma unroll
  for (int c4 = 0; c4 < 8; ++c4)
    o[c4] = relu4(acc[4*c4], acc[4*c4+1], acc[4*c4+2], acc[4*c4+3]);
}

// ---------- conv1: out = relu(sconv(f_tmp, W_conv)+b), c-half per blockIdx.y ----------
__global__ __launch_bounds__(256) void k_conv1(const float* __restrict__ fin,
    const float* __restrict__ Wg, const float* __restrict__ bg,
    const int* __restrict__ gk, float* __restrict__ fout, int N){
  __shared__ float Ws[27*32*16];
  const int c0 = blockIdx.y*16;
  for (int t = threadIdx.x*4; t < 27*32*16; t += 256*4){
    int r = t >> 4, col = t & 15;
    *(float4*)&Ws[t] = *(const float4*)&Wg[(size_t)r*32 + c0 + col];
  }
  __syncthreads();
  int i = blockIdx.x*blockDim.x + threadIdx.x;
  float acc[16];
#pragma unroll
  for (int c = 0; c < 16; ++c) acc[c] = bg[c0+c];
  gconv27<32,16>(acc, fin, Ws, gk, i, N);
  float4* o = (float4*)(fout + (size_t)i*32 + c0);
#pragma unroll
  for (int c4 = 0; c4 < 4; ++c4)
    o[c4] = relu4(acc[4*c4], acc[4*c4+1], acc[4*c4+2], acc[4*c4+3]);
}

// ---------- layer K1: a8 = relu(sconv(f,W00)+b00); b8 = relu(f@W10+b10) ----------
__global__ __launch_bounds__(256) void k_blk_a(const float* __restrict__ fO,
    const float* __restrict__ W00, const float* __restrict__ b00,
    const float* __restrict__ W10, const float* __restrict__ b10,
    const int* __restrict__ gk, float* __restrict__ a8, float* __restrict__ b8, int N){
  __shared__ float Ws[27*32*8 + 32*8];
  stage_f(Ws, W00, 27*32*8);
  stage_f(Ws + 27*32*8, W10, 32*8);
  __syncthreads();
  int i = blockIdx.x*blockDim.x + threadIdx.x;
  float acc[8];
#pragma unroll
  for (int c = 0; c < 8; ++c) acc[c] = b00[c];
  gconv27<32,8>(acc, fO, Ws, gk, i, N);
  float4* oa = (float4*)(a8 + (size_t)i*8);
  oa[0] = relu4(acc[0],acc[1],acc[2],acc[3]);
  oa[1] = relu4(acc[4],acc[5],acc[6],acc[7]);
  // dense branch start
  float xr[32]; loadrow<32>(xr, fO, i);
  float accb[8];
#pragma unroll
  for (int c = 0; c < 8; ++c) accb[c] = b10[c];
  fma_block<32,8>(accb, xr, Ws + 27*32*8);
  float4* ob = (float4*)(b8 + (size_t)i*8);
  ob[0] = relu4(accb[0],accb[1],accb[2],accb[3]);
  ob[1] = relu4(accb[4],accb[5],accb[6],accb[7]);
}

// ---------- layer K2: f_out[:,0:16] += sconv(a8,W01)+b01 ----------
__global__ __launch_bounds__(256) void k_blk_p0(const float* __restrict__ a8,
    const float* __restrict__ W01, const float* __restrict__ b01,
    const int* __restrict__ gk, float* __restrict__ fout, int N){
  __shared__ float Ws[27*8*16];
  stage_f(Ws, W01, 27*8*16);
  __syncthreads();
  int i = blockIdx.x*blockDim.x + threadIdx.x;
  float acc[16];
#pragma unroll
  for (int c = 0; c < 16; ++c) acc[c] = b01[c];
  gconv27<8,16>(acc, a8, Ws, gk, i, N);
  float4* o = (float4*)(fout + (size_t)i*32);
#pragma unroll
  for (int c4 = 0; c4 < 4; ++c4){
    float4 v = o[c4];
    v.x += acc[4*c4]; v.y += acc[4*c4+1]; v.z += acc[4*c4+2]; v.w += acc[4*c4+3];
    o[c4] = v;
  }
}

// ---------- layer K3: t8 = relu(sconv(b8,W11)+b11); f_out[:,16:32] += t8@W12+b12 ----------
__global__ __launch_bounds__(256) void k_blk_p1(const float* __restrict__ b8,
    const float* __restrict__ W11, const float* __restrict__ b11,
    const float* __restrict__ W12, const float* __restrict__ b12,
    const int* __restrict__ gk, float* __restrict__ fout, int N){
  __shared__ float Ws[27*8*8 + 8*16];
  stage_f(Ws, W11, 27*8*8);
  stage_f(Ws + 27*8*8, W12, 8*16);
  __syncthreads();
  int i = blockIdx.x*blockDim.x + threadIdx.x;
  float t8[8];
#pragma unroll
  for (int c = 0; c < 8; ++c) t8[c] = b11[c];
  gconv27<8,8>(t8, b8, Ws, gk, i, N);
#pragma unroll
  for (int c = 0; c < 8; ++c) t8[c] = fmaxf(t8[c], 0.f);
  float acc[16];
#pragma unroll
  for (int c = 0; c < 16; ++c) acc[c] = b12[c];
  fma_block<8,16>(acc, t8, Ws + 27*8*8);
  float4* o = (float4*)(fout + (size_t)i*32 + 16);
#pragma unroll
  for (int c4 = 0; c4 < 4; ++c4){
    float4 v = o[c4];
    v.x += acc[4*c4]; v.y += acc[4*c4+1]; v.z += acc[4*c4+2]; v.w += acc[4*c4+3];
    o[c4] = v;
  }
}

// ---------- classifier conv 32->1 ----------
__global__ __launch_bounds__(256) void k_cls(const float* __restrict__ fO,
    const float* __restrict__ Wc, const float* __restrict__ bc,
    const int* __restrict__ gk, float* __restrict__ cls, int N){
  __shared__ float Ws[27*32];
  stage_f(Ws, Wc, 27*32);
  __syncthreads();
  int i = blockIdx.x*blockDim.x + threadIdx.x;
  float acc[1] = { bc[0] };
  gconv27<32,1>(acc, fO, Ws, gk, i, N);
  cls[i] = acc[0];
}

// ---------- max/argmax (first-index tie-break) ----------
__global__ void k_reduce1(const float* __restrict__ s, float* __restrict__ pmax,
                          int* __restrict__ pidx, int n){
  __shared__ float sm[256]; __shared__ int si[256];
  int t = threadIdx.x;
  float v = -INFINITY; int vi = 0x7fffffff;
  for (int j = blockIdx.x*256 + t; j < n; j += gridDim.x*256){
    float w = s[j];
    if (w > v){ v = w; vi = j; }
  }
  sm[t] = v; si[t] = vi; __syncthreads();
  for (int o = 128; o > 0; o >>= 1){
    if (t < o){
      if (sm[t+o] > sm[t] || (sm[t+o] == sm[t] && si[t+o] < si[t])){ sm[t]=sm[t+o]; si[t]=si[t+o]; }
    }
    __syncthreads();
  }
  if (t == 0){ pmax[blockIdx.x] = sm[0]; pidx[blockIdx.x] = si[0]; }
}

__global__ void k_reduce2(const float* __restrict__ pmax, const int* __restrict__ pidx,
                          float* __restrict__ g, int nb){
  __shared__ float sm[256]; __shared__ int si[256];
  int t = threadIdx.x;
  sm[t] = (t < nb) ? pmax[t] : -INFINITY;
  si[t] = (t < nb) ? pidx[t] : 0x7fffffff;
  __syncthreads();
  for (int o = 128; o > 0; o >>= 1){
    if (t < o){
      if (sm[t+o] > sm[t] || (sm[t+o] == sm[t] && si[t+o] < si[t])){ sm[t]=sm[t+o]; si[t]=si[t+o]; }
    }
    __syncthreads();
  }
  if (t == 0){ g[0] = sm[0]; ((int*)g)[1] = si[0]; }
}

// ---------- finalize ----------
__global__ void k_final(const float* __restrict__ out, const float* __restrict__ cls,
                        const int* __restrict__ target, const float* __restrict__ g,
                        float* __restrict__ dout, int n_out){
  int idx = blockIdx.x*blockDim.x + threadIdx.x;
  if (idx >= n_out*32) return;
  int row = idx >> 5, c = idx & 31;
  float s = cls[row];
  bool keep = s > 0.f;
  if (g[0] < 0.f) keep = keep || (row == ((const int*)g)[1]);
  float km = keep ? 1.f : 0.f;
  dout[idx] = out[idx] * km;
  if (c == 0){
    dout[(size_t)n_out*32 + row] = s;
    dout[(size_t)n_out*33 + row] = (target[row] != 0) ? 1.f : 0.f;
    dout[(size_t)n_out*34 + row] = km;
  }
}

extern "C" void kernel_launch(void* const* d_in, const int* in_sizes, int n_in,
                              void* d_out, int out_size, void* d_ws, size_t ws_size,
                              hipStream_t stream){
  const float* x      = (const float*)d_in[0];
  const float* W_up   = (const float*)d_in[1];
  const float* b_up   = (const float*)d_in[2];
  const float* W_conv = (const float*)d_in[3];
  const float* b_conv = (const float*)d_in[4];
  const float* Wb00   = (const float*)d_in[5];
  const float* bb00   = (const float*)d_in[6];
  const float* Wb01   = (const float*)d_in[7];
  const float* bb01   = (const float*)d_in[8];
  const float* Wb10   = (const float*)d_in[9];
  const float* bb10   = (const float*)d_in[10];
  const float* Wb11   = (const float*)d_in[11];
  const float* bb11   = (const float*)d_in[12];
  const float* Wb12   = (const float*)d_in[13];
  const float* bb12   = (const float*)d_in[14];
  const float* W_cls  = (const float*)d_in[15];
  const float* b_cls  = (const float*)d_in[16];
  const int*   nbr_in = (const int*)d_in[17];
  const int*   nbr_out= (const int*)d_in[18];
  const int*   target = (const int*)d_in[19];

  const int n_out = in_sizes[19];      // 65536
  const int P     = in_sizes[17] / 27;
  const int pairsT = 27 * P;
  const int Nn    = n_out / 8;         // 8192 parent rows

  // workspace layout
  int*   g     = (int*)d_ws;                          // 27*N ints (k-major)
  float* ws    = (float*)d_ws + (size_t)n_out*27;
  float* f_tmp = ws;                                  // N*32 (relu(up))
  float* f_out = ws + (size_t)n_out*32;               // N*32
  float* a8    = ws + (size_t)n_out*64;               // N*8
  float* b8    = ws + (size_t)n_out*72;               // N*8
  float* cls   = ws + (size_t)n_out*80;               // N
  float* pmax  = ws + (size_t)n_out*81;               // 256
  int*   pidx  = (int*)(ws + (size_t)n_out*81 + 256); // 256
  float* gm    = ws + (size_t)n_out*81 + 512;         // [max, argmax]

  const int B = 256;
  const int GR = n_out / B;   // 256 row-blocks

  k_ginit<<<cdiv((long long)n_out*27/4,B),B,0,stream>>>(g, n_out*27/4);
  k_gbuild<<<cdiv((long long)pairsT,B),B,0,stream>>>(nbr_in, nbr_out, g, P, n_out);

  k_up<<<dim3(Nn/B,8),B,0,stream>>>(x, W_up, b_up, f_tmp, Nn);

  k_conv1<<<dim3(GR,2),B,0,stream>>>(f_tmp, W_conv, b_conv, g, f_out, n_out);

  for (int l = 0; l < 3; ++l){
    k_blk_a<<<GR,B,0,stream>>>(f_out, Wb00 + (size_t)l*27*32*8, bb00 + l*8,
                               Wb10 + (size_t)l*32*8, bb10 + l*8, g, a8, b8, n_out);
    k_blk_p0<<<GR,B,0,stream>>>(a8, Wb01 + (size_t)l*27*8*16, bb01 + l*16, g, f_out, n_out);
    k_blk_p1<<<GR,B,0,stream>>>(b8, Wb11 + (size_t)l*27*8*8, bb11 + l*8,
                                Wb12 + (size_t)l*8*16, bb12 + l*16, g, f_out, n_out);
  }

  k_cls<<<GR,B,0,stream>>>(f_out, W_cls, b_cls, g, cls, n_out);

  k_reduce1<<<256,256,0,stream>>>(cls, pmax, pidx, n_out);
  k_reduce2<<<1,256,0,stream>>>(pmax, pidx, gm, 256);

  k_final<<<cdiv((long long)n_out*32,B),B,0,stream>>>(f_out, cls, target, gm, (float*)d_out, n_out);
}

// Round 4
// 302.720 us; speedup vs baseline: 2.7545x; 1.1296x over previous
//
#include <hip/hip_runtime.h>
#include <math.h>

static inline int cdiv(long long a, int b){ return (int)((a + b - 1) / b); }
#define DEVINL __device__ __forceinline__

DEVINL float4 relu4(const float* a){
  return make_float4(fmaxf(a[0],0.f), fmaxf(a[1],0.f), fmaxf(a[2],0.f), fmaxf(a[3],0.f));
}

// ---------- gather table: g[k*N+i] = input row (n_out = zero pad row) ----------
__global__ void k_ginit(int* __restrict__ g, int n4, int val){
  int idx = blockIdx.x*blockDim.x + threadIdx.x;
  if (idx < n4) ((int4*)g)[idx] = make_int4(val,val,val,val);
}

__global__ void k_gbuild(const int* __restrict__ nin, const int* __restrict__ nout,
                         int* __restrict__ g, int P, int n_out){
  int p = blockIdx.x*blockDim.x + threadIdx.x;
  if (p >= 27*P) return;
  int oi = nout[p];
  if (oi >= n_out) return;
  int k = p / P;
  g[(size_t)k*n_out + oi] = nin[p];
}

// ---------- zero the pad rows ----------
__global__ void k_zpad(float* f_tmp, float* f_out, float* a8, float* b8, int N){
  int t = threadIdx.x;
  if (t < 32){ f_tmp[(size_t)N*32 + t] = 0.f; f_out[(size_t)N*32 + t] = 0.f; }
  if (t < 8){ a8[(size_t)N*8 + t] = 0.f; b8[(size_t)N*8 + t] = 0.f; }
}

// ---------- up: f[(n*8+kk)*32 + c0..3] = relu(x[n]·W_up[kk] + b_up) ----------
__global__ __launch_bounds__(256) void k_up(const float* __restrict__ x,
    const float* __restrict__ Wup, const float* __restrict__ bup,
    float* __restrict__ f, int Nn){
  __shared__ float Ws[64*32];
  const int kk = blockIdx.y;
  for (int e = threadIdx.x*4; e < 2048; e += 1024)
    *(float4*)&Ws[e] = *(const float4*)&Wup[(size_t)kk*2048 + e];
  __syncthreads();
  int t = threadIdx.x, cg = t & 7, nr = t >> 3;
  int n = blockIdx.x*32 + nr, c0 = cg*4;
  float4 b4 = *(const float4*)(bup + c0);
  float acc[4] = {b4.x, b4.y, b4.z, b4.w};
  float xr[64];
  const float4* xp = (const float4*)(x + (size_t)n*64);
#pragma unroll
  for (int q = 0; q < 16; ++q){
    float4 v = xp[q];
    xr[4*q]=v.x; xr[4*q+1]=v.y; xr[4*q+2]=v.z; xr[4*q+3]=v.w;
  }
#pragma unroll
  for (int cc = 0; cc < 64; ++cc){
    float4 w = *(const float4*)(Ws + cc*32 + c0);
    acc[0]=fmaf(xr[cc],w.x,acc[0]); acc[1]=fmaf(xr[cc],w.y,acc[1]);
    acc[2]=fmaf(xr[cc],w.z,acc[2]); acc[3]=fmaf(xr[cc],w.w,acc[3]);
  }
  *(float4*)(f + ((size_t)n*8 + kk)*32 + c0) = relu4(acc);
}

// ---------- conv1: 27x32x32, thread = (2 rows, 4-out group), k chunked 3x9 ----------
__global__ __launch_bounds__(512) void k_conv1(const float* __restrict__ fin,
    const float* __restrict__ Wg, const float* __restrict__ bg,
    const int* __restrict__ gk, float* __restrict__ fout, int N){
  __shared__ float Ws[9*32*32];
  int t = threadIdx.x, cg = t & 7, r2 = t >> 3;
  int row0 = blockIdx.x*128 + r2*2, c0 = cg*4;
  float4 b4 = *(const float4*)(bg + c0);
  float acc[2][4] = {{b4.x,b4.y,b4.z,b4.w},{b4.x,b4.y,b4.z,b4.w}};
  for (int ch = 0; ch < 3; ++ch){
    __syncthreads();
    for (int e = t*4; e < 9216; e += 2048)
      *(float4*)&Ws[e] = *(const float4*)&Wg[ch*9216 + e];
    __syncthreads();
#pragma unroll 1
    for (int kk = 0; kk < 9; ++kk){
      int k = ch*9 + kk;
      int j0 = gk[(size_t)k*N + row0];
      int j1 = gk[(size_t)k*N + row0 + 1];
      float fa[32], fb[32];
      const float4* p0 = (const float4*)(fin + (size_t)j0*32);
      const float4* p1 = (const float4*)(fin + (size_t)j1*32);
#pragma unroll
      for (int q = 0; q < 8; ++q){
        float4 v0 = p0[q], v1 = p1[q];
        fa[4*q]=v0.x; fa[4*q+1]=v0.y; fa[4*q+2]=v0.z; fa[4*q+3]=v0.w;
        fb[4*q]=v1.x; fb[4*q+1]=v1.y; fb[4*q+2]=v1.z; fb[4*q+3]=v1.w;
      }
      const float* wsk = Ws + kk*1024 + c0;
#pragma unroll
      for (int cc = 0; cc < 32; ++cc){
        float4 w = *(const float4*)(wsk + cc*32);
        acc[0][0]=fmaf(fa[cc],w.x,acc[0][0]); acc[0][1]=fmaf(fa[cc],w.y,acc[0][1]);
        acc[0][2]=fmaf(fa[cc],w.z,acc[0][2]); acc[0][3]=fmaf(fa[cc],w.w,acc[0][3]);
        acc[1][0]=fmaf(fb[cc],w.x,acc[1][0]); acc[1][1]=fmaf(fb[cc],w.y,acc[1][1]);
        acc[1][2]=fmaf(fb[cc],w.z,acc[1][2]); acc[1][3]=fmaf(fb[cc],w.w,acc[1][3]);
      }
    }
  }
  *(float4*)(fout + (size_t)row0*32 + c0)       = relu4(acc[0]);
  *(float4*)(fout + (size_t)(row0+1)*32 + c0)   = relu4(acc[1]);
}

// ---------- blk_a: a8 = relu(sconv32->8(f)), b8 = relu(f@W10+b10); thread=(row, cg2) ----------
__global__ __launch_bounds__(256) void k_blk_a(const float* __restrict__ fO,
    const float* __restrict__ W00, const float* __restrict__ b00,
    const float* __restrict__ W10, const float* __restrict__ b10,
    const int* __restrict__ gk, float* __restrict__ a8, float* __restrict__ b8, int N){
  __shared__ float Ws[27*32*8 + 32*8];
  int t = threadIdx.x;
  for (int e = t*4; e < 6912; e += 1024)
    *(float4*)&Ws[e] = *(const float4*)&W00[e];
  if (t*4 < 256)
    *(float4*)&Ws[6912 + t*4] = *(const float4*)&W10[t*4];
  __syncthreads();
  int cg = t & 1, r = t >> 1;
  int row = blockIdx.x*128 + r, c0 = cg*4;
  float4 b4 = *(const float4*)(b00 + c0);
  float acc[4] = {b4.x,b4.y,b4.z,b4.w};
#pragma unroll 1
  for (int k = 0; k < 27; ++k){
    int j = gk[(size_t)k*N + row];
    float fv[32];
    const float4* p = (const float4*)(fO + (size_t)j*32);
#pragma unroll
    for (int q = 0; q < 8; ++q){
      float4 v = p[q];
      fv[4*q]=v.x; fv[4*q+1]=v.y; fv[4*q+2]=v.z; fv[4*q+3]=v.w;
    }
    const float* wsk = Ws + k*256 + c0;
#pragma unroll
    for (int cc = 0; cc < 32; ++cc){
      float4 w = *(const float4*)(wsk + cc*8);
      acc[0]=fmaf(fv[cc],w.x,acc[0]); acc[1]=fmaf(fv[cc],w.y,acc[1]);
      acc[2]=fmaf(fv[cc],w.z,acc[2]); acc[3]=fmaf(fv[cc],w.w,acc[3]);
    }
  }
  *(float4*)(a8 + (size_t)row*8 + c0) = relu4(acc);
  // dense branch: own row
  float4 c4 = *(const float4*)(b10 + c0);
  float accb[4] = {c4.x,c4.y,c4.z,c4.w};
  float fv[32];
  const float4* p = (const float4*)(fO + (size_t)row*32);
#pragma unroll
  for (int q = 0; q < 8; ++q){
    float4 v = p[q];
    fv[4*q]=v.x; fv[4*q+1]=v.y; fv[4*q+2]=v.z; fv[4*q+3]=v.w;
  }
#pragma unroll
  for (int cc = 0; cc < 32; ++cc){
    float4 w = *(const float4*)(Ws + 6912 + cc*8 + c0);
    accb[0]=fmaf(fv[cc],w.x,accb[0]); accb[1]=fmaf(fv[cc],w.y,accb[1]);
    accb[2]=fmaf(fv[cc],w.z,accb[2]); accb[3]=fmaf(fv[cc],w.w,accb[3]);
  }
  *(float4*)(b8 + (size_t)row*8 + c0) = relu4(accb);
}

// ---------- blk_b: f_out[:,0:16] += sconv8->16(a8)+b01 ; f_out[:,16:32] += relu(sconv8->8(b8)+b11)@W12+b12
// thread = (row, cg4); t8 computed redundantly per cg ----------
__global__ __launch_bounds__(256) void k_blk_b(const float* __restrict__ a8,
    const float* __restrict__ b8,
    const float* __restrict__ W01, const float* __restrict__ b01,
    const float* __restrict__ W11, const float* __restrict__ b11,
    const float* __restrict__ W12, const float* __restrict__ b12,
    const int* __restrict__ gk, float* __restrict__ fout, int N){
  __shared__ float Ws[27*8*16 + 27*8*8 + 8*16];
  int t = threadIdx.x;
  for (int e = t*4; e < 3456; e += 1024)
    *(float4*)&Ws[e] = *(const float4*)&W01[e];
  for (int e = t*4; e < 1728; e += 1024)
    *(float4*)&Ws[3456 + e] = *(const float4*)&W11[e];
  if (t*4 < 128)
    *(float4*)&Ws[5184 + t*4] = *(const float4*)&W12[t*4];
  __syncthreads();
  int cg = t & 3, r = t >> 2;
  int row = blockIdx.x*64 + r, c0 = cg*4;
  float4 b4 = *(const float4*)(b01 + c0);
  float acc0[4] = {b4.x,b4.y,b4.z,b4.w};
  float t8[8];
#pragma unroll
  for (int c = 0; c < 8; ++c) t8[c] = b11[c];
#pragma unroll 1
  for (int k = 0; k < 27; ++k){
    int j = gk[(size_t)k*N + row];
    float av[8], bv[8];
    {
      const float4* pa = (const float4*)(a8 + (size_t)j*8);
      const float4* pb = (const float4*)(b8 + (size_t)j*8);
      float4 va0 = pa[0], va1 = pa[1], vb0 = pb[0], vb1 = pb[1];
      av[0]=va0.x; av[1]=va0.y; av[2]=va0.z; av[3]=va0.w;
      av[4]=va1.x; av[5]=va1.y; av[6]=va1.z; av[7]=va1.w;
      bv[0]=vb0.x; bv[1]=vb0.y; bv[2]=vb0.z; bv[3]=vb0.w;
      bv[4]=vb1.x; bv[5]=vb1.y; bv[6]=vb1.z; bv[7]=vb1.w;
    }
    const float* w01k = Ws + k*128 + c0;
    const float* w11k = Ws + 3456 + k*64;
#pragma unroll
    for (int cc = 0; cc < 8; ++cc){
      float4 w = *(const float4*)(w01k + cc*16);
      acc0[0]=fmaf(av[cc],w.x,acc0[0]); acc0[1]=fmaf(av[cc],w.y,acc0[1]);
      acc0[2]=fmaf(av[cc],w.z,acc0[2]); acc0[3]=fmaf(av[cc],w.w,acc0[3]);
      float4 u0 = *(const float4*)(w11k + cc*8);
      float4 u1 = *(const float4*)(w11k + cc*8 + 4);
      t8[0]=fmaf(bv[cc],u0.x,t8[0]); t8[1]=fmaf(bv[cc],u0.y,t8[1]);
      t8[2]=fmaf(bv[cc],u0.z,t8[2]); t8[3]=fmaf(bv[cc],u0.w,t8[3]);
      t8[4]=fmaf(bv[cc],u1.x,t8[4]); t8[5]=fmaf(bv[cc],u1.y,t8[5]);
      t8[6]=fmaf(bv[cc],u1.z,t8[6]); t8[7]=fmaf(bv[cc],u1.w,t8[7]);
    }
  }
#pragma unroll
  for (int c = 0; c < 8; ++c) t8[c] = fmaxf(t8[c], 0.f);
  float4 d4 = *(const float4*)(b12 + c0);
  float acc1[4] = {d4.x,d4.y,d4.z,d4.w};
#pragma unroll
  for (int cc = 0; cc < 8; ++cc){
    float4 w = *(const float4*)(Ws + 5184 + cc*16 + c0);
    acc1[0]=fmaf(t8[cc],w.x,acc1[0]); acc1[1]=fmaf(t8[cc],w.y,acc1[1]);
    acc1[2]=fmaf(t8[cc],w.z,acc1[2]); acc1[3]=fmaf(t8[cc],w.w,acc1[3]);
  }
  float4* o0 = (float4*)(fout + (size_t)row*32 + c0);
  float4* o1 = (float4*)(fout + (size_t)row*32 + 16 + c0);
  float4 v0 = *o0, v1 = *o1;
  v0.x+=acc0[0]; v0.y+=acc0[1]; v0.z+=acc0[2]; v0.w+=acc0[3];
  v1.x+=acc1[0]; v1.y+=acc1[1]; v1.z+=acc1[2]; v1.w+=acc1[3];
  *o0 = v0; *o1 = v1;
}

// ---------- cls: 32->1 conv; thread = (row, q4) cc-split + shuffle reduce ----------
__global__ __launch_bounds__(256) void k_cls(const float* __restrict__ fO,
    const float* __restrict__ Wc, const float* __restrict__ bc,
    const int* __restrict__ gk, float* __restrict__ cls, int N){
  __shared__ float Ws[27*32];
  int t = threadIdx.x;
  if (t < 216)
    *(float4*)&Ws[t*4] = *(const float4*)&Wc[t*4];
  __syncthreads();
  int q = t & 3, r = t >> 2;
  int row = blockIdx.x*64 + r;
  float acc = 0.f;
#pragma unroll 1
  for (int k = 0; k < 27; ++k){
    int j = gk[(size_t)k*N + row];
    const float4* p = (const float4*)(fO + (size_t)j*32 + q*8);
    float4 v0 = p[0], v1 = p[1];
    const float4* w = (const float4*)(Ws + k*32 + q*8);
    float4 w0 = w[0], w1 = w[1];
    acc = fmaf(v0.x,w0.x,acc); acc = fmaf(v0.y,w0.y,acc);
    acc = fmaf(v0.z,w0.z,acc); acc = fmaf(v0.w,w0.w,acc);
    acc = fmaf(v1.x,w1.x,acc); acc = fmaf(v1.y,w1.y,acc);
    acc = fmaf(v1.z,w1.z,acc); acc = fmaf(v1.w,w1.w,acc);
  }
  acc += __shfl_xor(acc, 1);
  acc += __shfl_xor(acc, 2);
  if (q == 0) cls[row] = acc + bc[0];
}

// ---------- max/argmax (first-index tie-break) ----------
__global__ void k_reduce1(const float* __restrict__ s, float* __restrict__ pmax,
                          int* __restrict__ pidx, int n){
  __shared__ float sm[256]; __shared__ int si[256];
  int t = threadIdx.x;
  float v = -INFINITY; int vi = 0x7fffffff;
  for (int j = blockIdx.x*256 + t; j < n; j += gridDim.x*256){
    float w = s[j];
    if (w > v){ v = w; vi = j; }
  }
  sm[t] = v; si[t] = vi; __syncthreads();
  for (int o = 128; o > 0; o >>= 1){
    if (t < o){
      if (sm[t+o] > sm[t] || (sm[t+o] == sm[t] && si[t+o] < si[t])){ sm[t]=sm[t+o]; si[t]=si[t+o]; }
    }
    __syncthreads();
  }
  if (t == 0){ pmax[blockIdx.x] = sm[0]; pidx[blockIdx.x] = si[0]; }
}

__global__ void k_reduce2(const float* __restrict__ pmax, const int* __restrict__ pidx,
                          float* __restrict__ g, int nb){
  __shared__ float sm[256]; __shared__ int si[256];
  int t = threadIdx.x;
  sm[t] = (t < nb) ? pmax[t] : -INFINITY;
  si[t] = (t < nb) ? pidx[t] : 0x7fffffff;
  __syncthreads();
  for (int o = 128; o > 0; o >>= 1){
    if (t < o){
      if (sm[t+o] > sm[t] || (sm[t+o] == sm[t] && si[t+o] < si[t])){ sm[t]=sm[t+o]; si[t]=si[t+o]; }
    }
    __syncthreads();
  }
  if (t == 0){ g[0] = sm[0]; ((int*)g)[1] = si[0]; }
}

// ---------- finalize ----------
__global__ void k_final(const float* __restrict__ out, const float* __restrict__ cls,
                        const int* __restrict__ target, const float* __restrict__ g,
                        float* __restrict__ dout, int n_out){
  int idx = blockIdx.x*blockDim.x + threadIdx.x;
  if (idx >= n_out*32) return;
  int row = idx >> 5, c = idx & 31;
  float s = cls[row];
  bool keep = s > 0.f;
  if (g[0] < 0.f) keep = keep || (row == ((const int*)g)[1]);
  float km = keep ? 1.f : 0.f;
  dout[idx] = out[idx] * km;
  if (c == 0){
    dout[(size_t)n_out*32 + row] = s;
    dout[(size_t)n_out*33 + row] = (target[row] != 0) ? 1.f : 0.f;
    dout[(size_t)n_out*34 + row] = km;
  }
}

extern "C" void kernel_launch(void* const* d_in, const int* in_sizes, int n_in,
                              void* d_out, int out_size, void* d_ws, size_t ws_size,
                              hipStream_t stream){
  const float* x      = (const float*)d_in[0];
  const float* W_up   = (const float*)d_in[1];
  const float* b_up   = (const float*)d_in[2];
  const float* W_conv = (const float*)d_in[3];
  const float* b_conv = (const float*)d_in[4];
  const float* Wb00   = (const float*)d_in[5];
  const float* bb00   = (const float*)d_in[6];
  const float* Wb01   = (const float*)d_in[7];
  const float* bb01   = (const float*)d_in[8];
  const float* Wb10   = (const float*)d_in[9];
  const float* bb10   = (const float*)d_in[10];
  const float* Wb11   = (const float*)d_in[11];
  const float* bb11   = (const float*)d_in[12];
  const float* Wb12   = (const float*)d_in[13];
  const float* bb12   = (const float*)d_in[14];
  const float* W_cls  = (const float*)d_in[15];
  const float* b_cls  = (const float*)d_in[16];
  const int*   nbr_in = (const int*)d_in[17];
  const int*   nbr_out= (const int*)d_in[18];
  const int*   target = (const int*)d_in[19];

  const int N = in_sizes[19];        // 65536
  const int P = in_sizes[17] / 27;
  const int pairsT = 27 * P;
  const int Nn = N / 8;              // 8192

  int*   g     = (int*)d_ws;                         // 27*N
  float* wsf   = (float*)d_ws + (size_t)27*N;
  float* f_tmp = wsf;                                // (N+1)*32
  float* f_out = f_tmp + (size_t)(N+1)*32;           // (N+1)*32
  float* a8    = f_out + (size_t)(N+1)*32;           // (N+1)*8
  float* b8    = a8 + (size_t)(N+1)*8;               // (N+1)*8
  float* cls   = b8 + (size_t)(N+1)*8;               // N
  float* pmax  = cls + N;                            // 256
  int*   pidx  = (int*)(pmax + 256);                 // 256
  float* gm    = pmax + 512;                         // [max, argmax]

  const int B = 256;

  k_ginit<<<cdiv((long long)27*N/4,B),B,0,stream>>>(g, 27*N/4, N);
  k_gbuild<<<cdiv((long long)pairsT,B),B,0,stream>>>(nbr_in, nbr_out, g, P, N);
  k_zpad<<<1,64,0,stream>>>(f_tmp, f_out, a8, b8, N);

  k_up<<<dim3(Nn/32,8),B,0,stream>>>(x, W_up, b_up, f_tmp, Nn);

  k_conv1<<<N/128,512,0,stream>>>(f_tmp, W_conv, b_conv, g, f_out, N);

  for (int l = 0; l < 3; ++l){
    k_blk_a<<<N/128,B,0,stream>>>(f_out, Wb00 + (size_t)l*6912, bb00 + l*8,
                                  Wb10 + (size_t)l*256, bb10 + l*8, g, a8, b8, N);
    k_blk_b<<<N/64,B,0,stream>>>(a8, b8,
                                 Wb01 + (size_t)l*3456, bb01 + l*16,
                                 Wb11 + (size_t)l*1728, bb11 + l*8,
                                 Wb12 + (size_t)l*128, bb12 + l*16,
                                 g, f_out, N);
  }

  k_cls<<<N/64,B,0,stream>>>(f_out, W_cls, b_cls, g, cls, N);

  k_reduce1<<<256,256,0,stream>>>(cls, pmax, pidx, N);
  k_reduce2<<<1,256,0,stream>>>(pmax, pidx, gm, 256);

  k_final<<<cdiv((long long)N*32,B),B,0,stream>>>(f_out, cls, target, gm, (float*)d_out, N);
}

// Round 5
// 213.873 us; speedup vs baseline: 3.8988x; 1.4154x over previous
//
#include <hip/hip_runtime.h>
#include <math.h>

static inline int cdiv(long long a, int b){ return (int)((a + b - 1) / b); }
#define DEVINL __device__ __forceinline__

DEVINL float4 relu4(const float* a){
  return make_float4(fmaxf(a[0],0.f), fmaxf(a[1],0.f), fmaxf(a[2],0.f), fmaxf(a[3],0.f));
}

DEVINL void load32(float* fv, const float* __restrict__ p){
#pragma unroll
  for (int q = 0; q < 8; ++q){
    float4 v = ((const float4*)p)[q];
    fv[4*q]=v.x; fv[4*q+1]=v.y; fv[4*q+2]=v.z; fv[4*q+3]=v.w;
  }
}
DEVINL void load8(float* fv, const float* __restrict__ p){
#pragma unroll
  for (int q = 0; q < 2; ++q){
    float4 v = ((const float4*)p)[q];
    fv[4*q]=v.x; fv[4*q+1]=v.y; fv[4*q+2]=v.z; fv[4*q+3]=v.w;
  }
}

// tap index for sibling pair: d = o' - o (componentwise), k = (dx+1)*9+(dy+1)*3+(dz+1)
DEVINL int sib_k(int o, int op){
  return 13 + 9*(((op>>2)&1) - ((o>>2)&1))
            + 3*(((op>>1)&1) - ((o>>1)&1))
            +   ((op&1) - (o&1));
}

// ---------- remainder list build: cross-parent valid neighbors only ----------
__global__ void k_rinit(int* __restrict__ cnt, int n){
  int i = blockIdx.x*blockDim.x + threadIdx.x;
  if (i < n) cnt[i] = 0;
}

__global__ void k_rbuild(const int* __restrict__ nin, const int* __restrict__ nout,
                         int* __restrict__ cnt, int* __restrict__ rem, int P, int N){
  int p = blockIdx.x*blockDim.x + threadIdx.x;
  if (p >= 27*P) return;
  int oi = nout[p];
  if (oi >= N) return;                 // padded slot
  int j = nin[p];
  if ((oi >> 3) == (j >> 3)) return;   // sibling: handled statically
  int k = p / P;
  int pos = atomicAdd(&cnt[oi], 1);
  rem[(size_t)oi*20 + pos] = (j << 5) | k;
}

// ---------- up: f[(n*8+kk)*32 + c0..3] = relu(x[n]·W_up[kk] + b_up) ----------
__global__ __launch_bounds__(256) void k_up(const float* __restrict__ x,
    const float* __restrict__ Wup, const float* __restrict__ bup,
    float* __restrict__ f, int Nn){
  __shared__ float Ws[64*32];
  const int kk = blockIdx.y;
  for (int e = threadIdx.x*4; e < 2048; e += 1024)
    *(float4*)&Ws[e] = *(const float4*)&Wup[(size_t)kk*2048 + e];
  __syncthreads();
  int t = threadIdx.x, cg = t & 7, nr = t >> 3;
  int n = blockIdx.x*32 + nr, c0 = cg*4;
  float4 b4 = *(const float4*)(bup + c0);
  float acc[4] = {b4.x, b4.y, b4.z, b4.w};
  float xr[64];
  const float4* xp = (const float4*)(x + (size_t)n*64);
#pragma unroll
  for (int q = 0; q < 16; ++q){
    float4 v = xp[q];
    xr[4*q]=v.x; xr[4*q+1]=v.y; xr[4*q+2]=v.z; xr[4*q+3]=v.w;
  }
#pragma unroll
  for (int cc = 0; cc < 64; ++cc){
    float4 w = *(const float4*)(Ws + cc*32 + c0);
    acc[0]=fmaf(xr[cc],w.x,acc[0]); acc[1]=fmaf(xr[cc],w.y,acc[1]);
    acc[2]=fmaf(xr[cc],w.z,acc[2]); acc[3]=fmaf(xr[cc],w.w,acc[3]);
  }
  *(float4*)(f + ((size_t)n*8 + kk)*32 + c0) = relu4(acc);
}

// ---------- conv1: 27x32x32, sibling-static + remainder; c-half per blockIdx.y ----------
// LDS: W half [27][32][16], k-stride padded to 516 floats
__global__ __launch_bounds__(512) void k_conv1(const float* __restrict__ fin,
    const float* __restrict__ Wg, const float* __restrict__ bg,
    const int* __restrict__ cnt, const int* __restrict__ rem,
    float* __restrict__ fout, int N){
  __shared__ float Ws[27*516];
  const int ch = blockIdx.y;
  int t = threadIdx.x;
  for (int m = t; m < 3456; m += 512){
    int k = m >> 7, r = m & 127, cc = r >> 2, q = r & 3;
    *(float4*)&Ws[k*516 + cc*16 + q*4] =
      *(const float4*)&Wg[((size_t)(k*32 + cc))*32 + ch*16 + q*4];
  }
  __syncthreads();
  int cg = t & 3, r = t >> 2;
  int row = blockIdx.x*128 + r;
  int o = row & 7, base = row & ~7, c0 = cg*4;
  float4 b4 = *(const float4*)(bg + ch*16 + c0);
  float acc[4] = {b4.x,b4.y,b4.z,b4.w};
  float fv[32];
#pragma unroll
  for (int op = 0; op < 8; ++op){
    int kk = sib_k(o, op);
    load32(fv, fin + (size_t)(base+op)*32);
    const float* wk = Ws + kk*516 + c0;
#pragma unroll
    for (int cc = 0; cc < 32; ++cc){
      float4 w = *(const float4*)(wk + cc*16);
      acc[0]=fmaf(fv[cc],w.x,acc[0]); acc[1]=fmaf(fv[cc],w.y,acc[1]);
      acc[2]=fmaf(fv[cc],w.z,acc[2]); acc[3]=fmaf(fv[cc],w.w,acc[3]);
    }
  }
  int nrm = cnt[row];
  for (int s = 0; s < nrm; ++s){
    int e = rem[(size_t)row*20 + s];
    int kk = e & 31, j = e >> 5;
    load32(fv, fin + (size_t)j*32);
    const float* wk = Ws + kk*516 + c0;
#pragma unroll
    for (int cc = 0; cc < 32; ++cc){
      float4 w = *(const float4*)(wk + cc*16);
      acc[0]=fmaf(fv[cc],w.x,acc[0]); acc[1]=fmaf(fv[cc],w.y,acc[1]);
      acc[2]=fmaf(fv[cc],w.z,acc[2]); acc[3]=fmaf(fv[cc],w.w,acc[3]);
    }
  }
  *(float4*)(fout + (size_t)row*32 + ch*16 + c0) = relu4(acc);
}

// ---------- blk_a: a8 = relu(sconv32->8(f)+b00); b8 = relu(f@W10+b10) ----------
__global__ __launch_bounds__(256) void k_blk_a(const float* __restrict__ fO,
    const float* __restrict__ W00, const float* __restrict__ b00,
    const float* __restrict__ W10, const float* __restrict__ b10,
    const int* __restrict__ cnt, const int* __restrict__ rem,
    float* __restrict__ a8, float* __restrict__ b8, int N){
  __shared__ float Ws[27*260 + 256];
  int t = threadIdx.x;
  for (int m = t; m < 1728; m += 256){
    int k = m >> 6, r = m & 63, cc = r >> 1, q = r & 1;
    *(float4*)&Ws[k*260 + cc*8 + q*4] = ((const float4*)W00)[m];
  }
  if (t < 64) *(float4*)&Ws[27*260 + t*4] = ((const float4*)W10)[t];
  __syncthreads();
  int cg = t & 1, r = t >> 1;
  int row = blockIdx.x*128 + r;
  int o = row & 7, base = row & ~7, c0 = cg*4;
  float4 b4 = *(const float4*)(b00 + c0);
  float acc[4] = {b4.x,b4.y,b4.z,b4.w};
  float fv[32];
#pragma unroll
  for (int op = 0; op < 8; ++op){
    int kk = sib_k(o, op);
    load32(fv, fO + (size_t)(base+op)*32);
    const float* wk = Ws + kk*260 + c0;
#pragma unroll
    for (int cc = 0; cc < 32; ++cc){
      float4 w = *(const float4*)(wk + cc*8);
      acc[0]=fmaf(fv[cc],w.x,acc[0]); acc[1]=fmaf(fv[cc],w.y,acc[1]);
      acc[2]=fmaf(fv[cc],w.z,acc[2]); acc[3]=fmaf(fv[cc],w.w,acc[3]);
    }
  }
  int nrm = cnt[row];
  for (int s = 0; s < nrm; ++s){
    int e = rem[(size_t)row*20 + s];
    int kk = e & 31, j = e >> 5;
    load32(fv, fO + (size_t)j*32);
    const float* wk = Ws + kk*260 + c0;
#pragma unroll
    for (int cc = 0; cc < 32; ++cc){
      float4 w = *(const float4*)(wk + cc*8);
      acc[0]=fmaf(fv[cc],w.x,acc[0]); acc[1]=fmaf(fv[cc],w.y,acc[1]);
      acc[2]=fmaf(fv[cc],w.z,acc[2]); acc[3]=fmaf(fv[cc],w.w,acc[3]);
    }
  }
  *(float4*)(a8 + (size_t)row*8 + c0) = relu4(acc);
  // dense branch on own row
  load32(fv, fO + (size_t)row*32);
  float4 d4 = *(const float4*)(b10 + c0);
  float accb[4] = {d4.x,d4.y,d4.z,d4.w};
#pragma unroll
  for (int cc = 0; cc < 32; ++cc){
    float4 w = *(const float4*)(Ws + 27*260 + cc*8 + c0);
    accb[0]=fmaf(fv[cc],w.x,accb[0]); accb[1]=fmaf(fv[cc],w.y,accb[1]);
    accb[2]=fmaf(fv[cc],w.z,accb[2]); accb[3]=fmaf(fv[cc],w.w,accb[3]);
  }
  *(float4*)(b8 + (size_t)row*8 + c0) = relu4(accb);
}

// ---------- blk_b: fout[:,0:16] += sconv8->16(a8)+b01 ;
//            fout[:,16:32] += relu(sconv8->8(b8)+b11)@W12+b12 ----------
__global__ __launch_bounds__(256) void k_blk_b(const float* __restrict__ a8,
    const float* __restrict__ b8,
    const float* __restrict__ W01, const float* __restrict__ b01,
    const float* __restrict__ W11, const float* __restrict__ b11,
    const float* __restrict__ W12, const float* __restrict__ b12,
    const int* __restrict__ cnt, const int* __restrict__ rem,
    float* __restrict__ fout, int N){
  __shared__ float Ws[27*132 + 27*68 + 128];   // 3564 + 1836 + 128
  int t = threadIdx.x;
  for (int m = t; m < 864; m += 256){
    int k = m >> 5, r = m & 31, cc = r >> 2, q = r & 3;
    *(float4*)&Ws[k*132 + cc*16 + q*4] = ((const float4*)W01)[m];
  }
  for (int m = t; m < 432; m += 256){
    int k = m >> 4, r = m & 15, cc = r >> 1, q = r & 1;
    *(float4*)&Ws[3564 + k*68 + cc*8 + q*4] = ((const float4*)W11)[m];
  }
  if (t < 32) *(float4*)&Ws[5400 + t*4] = ((const float4*)W12)[t];
  __syncthreads();
  int cg = t & 3, r = t >> 2;
  int row = blockIdx.x*64 + r;
  int o = row & 7, base = row & ~7, c0 = cg*4;
  float4 b4 = *(const float4*)(b01 + c0);
  float acc0[4] = {b4.x,b4.y,b4.z,b4.w};
  float t8[8];
#pragma unroll
  for (int c = 0; c < 8; ++c) t8[c] = b11[c];
  float av[8], bv[8];
#pragma unroll
  for (int op = 0; op < 8; ++op){
    int kk = sib_k(o, op);
    load8(av, a8 + (size_t)(base+op)*8);
    load8(bv, b8 + (size_t)(base+op)*8);
    const float* w01k = Ws + kk*132 + c0;
    const float* w11k = Ws + 3564 + kk*68;
#pragma unroll
    for (int cc = 0; cc < 8; ++cc){
      float4 w = *(const float4*)(w01k + cc*16);
      acc0[0]=fmaf(av[cc],w.x,acc0[0]); acc0[1]=fmaf(av[cc],w.y,acc0[1]);
      acc0[2]=fmaf(av[cc],w.z,acc0[2]); acc0[3]=fmaf(av[cc],w.w,acc0[3]);
      float4 u0 = *(const float4*)(w11k + cc*8);
      float4 u1 = *(const float4*)(w11k + cc*8 + 4);
      t8[0]=fmaf(bv[cc],u0.x,t8[0]); t8[1]=fmaf(bv[cc],u0.y,t8[1]);
      t8[2]=fmaf(bv[cc],u0.z,t8[2]); t8[3]=fmaf(bv[cc],u0.w,t8[3]);
      t8[4]=fmaf(bv[cc],u1.x,t8[4]); t8[5]=fmaf(bv[cc],u1.y,t8[5]);
      t8[6]=fmaf(bv[cc],u1.z,t8[6]); t8[7]=fmaf(bv[cc],u1.w,t8[7]);
    }
  }
  int nrm = cnt[row];
  for (int s = 0; s < nrm; ++s){
    int e = rem[(size_t)row*20 + s];
    int kk = e & 31, j = e >> 5;
    load8(av, a8 + (size_t)j*8);
    load8(bv, b8 + (size_t)j*8);
    const float* w01k = Ws + kk*132 + c0;
    const float* w11k = Ws + 3564 + kk*68;
#pragma unroll
    for (int cc = 0; cc < 8; ++cc){
      float4 w = *(const float4*)(w01k + cc*16);
      acc0[0]=fmaf(av[cc],w.x,acc0[0]); acc0[1]=fmaf(av[cc],w.y,acc0[1]);
      acc0[2]=fmaf(av[cc],w.z,acc0[2]); acc0[3]=fmaf(av[cc],w.w,acc0[3]);
      float4 u0 = *(const float4*)(w11k + cc*8);
      float4 u1 = *(const float4*)(w11k + cc*8 + 4);
      t8[0]=fmaf(bv[cc],u0.x,t8[0]); t8[1]=fmaf(bv[cc],u0.y,t8[1]);
      t8[2]=fmaf(bv[cc],u0.z,t8[2]); t8[3]=fmaf(bv[cc],u0.w,t8[3]);
      t8[4]=fmaf(bv[cc],u1.x,t8[4]); t8[5]=fmaf(bv[cc],u1.y,t8[5]);
      t8[6]=fmaf(bv[cc],u1.z,t8[6]); t8[7]=fmaf(bv[cc],u1.w,t8[7]);
    }
  }
#pragma unroll
  for (int c = 0; c < 8; ++c) t8[c] = fmaxf(t8[c], 0.f);
  float4 d4 = *(const float4*)(b12 + c0);
  float acc1[4] = {d4.x,d4.y,d4.z,d4.w};
#pragma unroll
  for (int cc = 0; cc < 8; ++cc){
    float4 w = *(const float4*)(Ws + 5400 + cc*16 + c0);
    acc1[0]=fmaf(t8[cc],w.x,acc1[0]); acc1[1]=fmaf(t8[cc],w.y,acc1[1]);
    acc1[2]=fmaf(t8[cc],w.z,acc1[2]); acc1[3]=fmaf(t8[cc],w.w,acc1[3]);
  }
  float4* o0 = (float4*)(fout + (size_t)row*32 + c0);
  float4* o1 = (float4*)(fout + (size_t)row*32 + 16 + c0);
  float4 v0 = *o0, v1 = *o1;
  v0.x+=acc0[0]; v0.y+=acc0[1]; v0.z+=acc0[2]; v0.w+=acc0[3];
  v1.x+=acc1[0]; v1.y+=acc1[1]; v1.z+=acc1[2]; v1.w+=acc1[3];
  *o0 = v0; *o1 = v1;
}

// ---------- cls: 32->1 conv, one thread per row ----------
__global__ __launch_bounds__(256) void k_cls(const float* __restrict__ fO,
    const float* __restrict__ Wc, const float* __restrict__ bc,
    const int* __restrict__ cnt, const int* __restrict__ rem,
    float* __restrict__ cls, int N){
  __shared__ float Ws[27*36];
  int t = threadIdx.x;
  if (t < 216){
    int k = t >> 3, r = t & 7;
    *(float4*)&Ws[k*36 + r*4] = ((const float4*)Wc)[t];
  }
  __syncthreads();
  int row = blockIdx.x*256 + t;
  int o = row & 7, base = row & ~7;
  float acc = 0.f;
  float fv[32];
#pragma unroll
  for (int op = 0; op < 8; ++op){
    int kk = sib_k(o, op);
    load32(fv, fO + (size_t)(base+op)*32);
    const float* wk = Ws + kk*36;
#pragma unroll
    for (int c4 = 0; c4 < 8; ++c4){
      float4 w = *(const float4*)(wk + c4*4);
      acc = fmaf(fv[4*c4],w.x,acc);   acc = fmaf(fv[4*c4+1],w.y,acc);
      acc = fmaf(fv[4*c4+2],w.z,acc); acc = fmaf(fv[4*c4+3],w.w,acc);
    }
  }
  int nrm = cnt[row];
  for (int s = 0; s < nrm; ++s){
    int e = rem[(size_t)row*20 + s];
    int kk = e & 31, j = e >> 5;
    load32(fv, fO + (size_t)j*32);
    const float* wk = Ws + kk*36;
#pragma unroll
    for (int c4 = 0; c4 < 8; ++c4){
      float4 w = *(const float4*)(wk + c4*4);
      acc = fmaf(fv[4*c4],w.x,acc);   acc = fmaf(fv[4*c4+1],w.y,acc);
      acc = fmaf(fv[4*c4+2],w.z,acc); acc = fmaf(fv[4*c4+3],w.w,acc);
    }
  }
  cls[row] = acc + bc[0];
}

// ---------- max/argmax (first-index tie-break) ----------
__global__ void k_reduce1(const float* __restrict__ s, float* __restrict__ pmax,
                          int* __restrict__ pidx, int n){
  __shared__ float sm[256]; __shared__ int si[256];
  int t = threadIdx.x;
  float v = -INFINITY; int vi = 0x7fffffff;
  for (int j = blockIdx.x*256 + t; j < n; j += gridDim.x*256){
    float w = s[j];
    if (w > v){ v = w; vi = j; }
  }
  sm[t] = v; si[t] = vi; __syncthreads();
  for (int o = 128; o > 0; o >>= 1){
    if (t < o){
      if (sm[t+o] > sm[t] || (sm[t+o] == sm[t] && si[t+o] < si[t])){ sm[t]=sm[t+o]; si[t]=si[t+o]; }
    }
    __syncthreads();
  }
  if (t == 0){ pmax[blockIdx.x] = sm[0]; pidx[blockIdx.x] = si[0]; }
}

__global__ void k_reduce2(const float* __restrict__ pmax, const int* __restrict__ pidx,
                          float* __restrict__ g, int nb){
  __shared__ float sm[256]; __shared__ int si[256];
  int t = threadIdx.x;
  sm[t] = (t < nb) ? pmax[t] : -INFINITY;
  si[t] = (t < nb) ? pidx[t] : 0x7fffffff;
  __syncthreads();
  for (int o = 128; o > 0; o >>= 1){
    if (t < o){
      if (sm[t+o] > sm[t] || (sm[t+o] == sm[t] && si[t+o] < si[t])){ sm[t]=sm[t+o]; si[t]=si[t+o]; }
    }
    __syncthreads();
  }
  if (t == 0){ g[0] = sm[0]; ((int*)g)[1] = si[0]; }
}

// ---------- finalize ----------
__global__ void k_final(const float* __restrict__ out, const float* __restrict__ cls,
                        const int* __restrict__ target, const float* __restrict__ g,
                        float* __restrict__ dout, int n_out){
  int idx = blockIdx.x*blockDim.x + threadIdx.x;
  if (idx >= n_out*32) return;
  int row = idx >> 5, c = idx & 31;
  float s = cls[row];
  bool keep = s > 0.f;
  if (g[0] < 0.f) keep = keep || (row == ((const int*)g)[1]);
  float km = keep ? 1.f : 0.f;
  dout[idx] = out[idx] * km;
  if (c == 0){
    dout[(size_t)n_out*32 + row] = s;
    dout[(size_t)n_out*33 + row] = (target[row] != 0) ? 1.f : 0.f;
    dout[(size_t)n_out*34 + row] = km;
  }
}

extern "C" void kernel_launch(void* const* d_in, const int* in_sizes, int n_in,
                              void* d_out, int out_size, void* d_ws, size_t ws_size,
                              hipStream_t stream){
  const float* x      = (const float*)d_in[0];
  const float* W_up   = (const float*)d_in[1];
  const float* b_up   = (const float*)d_in[2];
  const float* W_conv = (const float*)d_in[3];
  const float* b_conv = (const float*)d_in[4];
  const float* Wb00   = (const float*)d_in[5];
  const float* bb00   = (const float*)d_in[6];
  const float* Wb01   = (const float*)d_in[7];
  const float* bb01   = (const float*)d_in[8];
  const float* Wb10   = (const float*)d_in[9];
  const float* bb10   = (const float*)d_in[10];
  const float* Wb11   = (const float*)d_in[11];
  const float* bb11   = (const float*)d_in[12];
  const float* Wb12   = (const float*)d_in[13];
  const float* bb12   = (const float*)d_in[14];
  const float* W_cls  = (const float*)d_in[15];
  const float* b_cls  = (const float*)d_in[16];
  const int*   nbr_in = (const int*)d_in[17];
  const int*   nbr_out= (const int*)d_in[18];
  const int*   target = (const int*)d_in[19];

  const int N = in_sizes[19];        // 65536
  const int P = in_sizes[17] / 27;
  const int pairsT = 27 * P;
  const int Nn = N / 8;              // 8192

  int*   cnt  = (int*)d_ws;                          // N
  int*   rem  = cnt + N;                             // N*20
  float* wsf  = (float*)(rem + (size_t)N*20);
  float* f_tmp = wsf;                                // N*32
  float* f_out = f_tmp + (size_t)N*32;               // N*32
  float* a8    = f_out + (size_t)N*32;               // N*8
  float* b8    = a8 + (size_t)N*8;                   // N*8
  float* cls   = b8 + (size_t)N*8;                   // N
  float* pmax  = cls + N;                            // 256
  int*   pidx  = (int*)(pmax + 256);                 // 256
  float* gm    = pmax + 512;                         // [max, argmax]

  const int B = 256;

  k_rinit<<<cdiv(N,B),B,0,stream>>>(cnt, N);
  k_rbuild<<<cdiv((long long)pairsT,B),B,0,stream>>>(nbr_in, nbr_out, cnt, rem, P, N);

  k_up<<<dim3(Nn/32,8),B,0,stream>>>(x, W_up, b_up, f_tmp, Nn);

  k_conv1<<<dim3(N/128,2),512,0,stream>>>(f_tmp, W_conv, b_conv, cnt, rem, f_out, N);

  for (int l = 0; l < 3; ++l){
    k_blk_a<<<N/128,B,0,stream>>>(f_out, Wb00 + (size_t)l*6912, bb00 + l*8,
                                  Wb10 + (size_t)l*256, bb10 + l*8, cnt, rem, a8, b8, N);
    k_blk_b<<<N/64,B,0,stream>>>(a8, b8,
                                 Wb01 + (size_t)l*3456, bb01 + l*16,
                                 Wb11 + (size_t)l*1728, bb11 + l*8,
                                 Wb12 + (size_t)l*128, bb12 + l*16,
                                 cnt, rem, f_out, N);
  }

  k_cls<<<N/256,B,0,stream>>>(f_out, W_cls, b_cls, cnt, rem, cls, N);

  k_reduce1<<<256,256,0,stream>>>(cls, pmax, pidx, N);
  k_reduce2<<<1,256,0,stream>>>(pmax, pidx, gm, 256);

  k_final<<<cdiv((long long)N*32,B),B,0,stream>>>(f_out, cls, target, gm, (float*)d_out, N);
}